// Round 2
// 598.490 us; speedup vs baseline: 1.0940x; 1.0940x over previous
//
#include <hip/hip_runtime.h>
#include <cmath>

#define TS 2048   // sequence
#define TH 768    // hidden
#define TNH 12    // heads
#define THD 64    // head dim
#define TNF 128   // rff features
#define KC 192    // concat K for scores (64 dot + 128 rff)

typedef __attribute__((ext_vector_type(4))) short s16x4;     // NOTE: 'short4' collides with HIP's vector types
typedef __attribute__((ext_vector_type(8))) short short8;
typedef __attribute__((ext_vector_type(8))) __bf16 bf16x8;   // matches builtin signature V8y
typedef __attribute__((ext_vector_type(4))) float floatx4;

// ---------------- fp32 <-> bf16 helpers ----------------
__device__ __forceinline__ short f2bf(float x) {
    union { float f; unsigned u; } v; v.f = x;
    unsigned r = v.u + 0x7FFFu + ((v.u >> 16) & 1u);   // round-nearest-even
    return (short)(r >> 16);
}
__device__ __forceinline__ float bf2f(short x) {
    union { unsigned u; float f; } v;
    v.u = ((unsigned)(unsigned short)x) << 16;
    return v.f;
}

// ---------------- wave helpers (wave = 64) ----------------
__device__ __forceinline__ float waveReduceSum(float v) {
#pragma unroll
    for (int off = 32; off >= 1; off >>= 1) v += __shfl_xor(v, off, 64);
    return v;
}
__device__ __forceinline__ float waveReduceMax(float v) {
#pragma unroll
    for (int off = 32; off >= 1; off >>= 1) v = fmaxf(v, __shfl_xor(v, off, 64));
    return v;
}

// ---------------- fp32 inner-product microkernel (kept for small GEMMs) ----------------
__device__ __forceinline__ void fma16(float (&acc)[4][4], const float* pa, const float* pb) {
#pragma unroll
    for (int kk = 0; kk < 32; ++kk) {
        float4 a = *(const float4*)(pa + kk * 68);
        float4 b = *(const float4*)(pb + kk * 68);
        float av[4] = {a.x, a.y, a.z, a.w};
        float bv[4] = {b.x, b.y, b.z, b.w};
#pragma unroll
        for (int i = 0; i < 4; ++i)
#pragma unroll
            for (int j = 0; j < 4; ++j) acc[i][j] += av[i] * bv[j];
    }
}

// ---------------- QKV projection: Y = X @ W^T + b, scatter to (h,s,d) ----------------
// z==0 (q): dq fp32 + Qc[row][0:64] = bf16(0.1125 * q)   (alpha/sqrt(HD) folded)
// z==1 (k): dk fp32 + Kc[row][0:64] = bf16(k)
// z==2 (v): Vb[h][d][t] = bf16(v)  (transposed for the PV MFMA B-operand; no fp32 copy)
__global__ __launch_bounds__(256) void k_proj_qkv(
    const float* __restrict__ X,
    const float* __restrict__ W0, const float* __restrict__ b0,
    const float* __restrict__ W1, const float* __restrict__ b1,
    const float* __restrict__ W2, const float* __restrict__ b2,
    float* __restrict__ dq, float* __restrict__ dk, short* __restrict__ Vb,
    short* __restrict__ Qc, short* __restrict__ Kc) {
    __shared__ float As[32][68];
    __shared__ float Bs[32][68];
    const int z = blockIdx.z;
    const float* W = (z == 0) ? W0 : ((z == 1) ? W1 : W2);
    const float* bias = (z == 0) ? b0 : ((z == 1) ? b1 : b2);
    float* dst = (z == 0) ? dq : dk;   // z==2 writes Vb instead
    const int n0 = blockIdx.x * 64;
    const int m0 = blockIdx.y * 64;
    const int tid = threadIdx.x;
    float acc[4][4] = {};
    for (int k0 = 0; k0 < TH; k0 += 32) {
#pragma unroll
        for (int l = 0; l < 2; ++l) {
            int i = tid + l * 256;
            int row = i >> 3, col = (i & 7) << 2;
            float4 a = *(const float4*)&X[(m0 + row) * TH + k0 + col];
            As[col + 0][row] = a.x; As[col + 1][row] = a.y;
            As[col + 2][row] = a.z; As[col + 3][row] = a.w;
            float4 b = *(const float4*)&W[(n0 + row) * TH + k0 + col];
            Bs[col + 0][row] = b.x; Bs[col + 1][row] = b.y;
            Bs[col + 2][row] = b.z; Bs[col + 3][row] = b.w;
        }
        __syncthreads();
        fma16(acc, &As[0][0] + ((tid >> 4) << 2), &Bs[0][0] + ((tid & 15) << 2));
        __syncthreads();
    }
    const int mb = m0 + ((tid >> 4) << 2);
    const int nb = n0 + ((tid & 15) << 2);
    if (z == 2) {
        // transposed bf16 V: Vb[(h*64+d)*TS + t], pack 4 consecutive t per 8B store
#pragma unroll
        for (int j = 0; j < 4; ++j) {
            int n = nb + j;
            int h = n >> 6, d = n & 63;
            float bv = bias[n];
            s16x4 pk;
#pragma unroll
            for (int i = 0; i < 4; ++i) pk[i] = f2bf(acc[i][j] + bv);
            *(s16x4*)&Vb[(size_t)(h * THD + d) * TS + mb] = pk;
        }
    } else {
#pragma unroll
        for (int i = 0; i < 4; ++i)
#pragma unroll
            for (int j = 0; j < 4; ++j) {
                int n = nb + j;
                float val = acc[i][j] + bias[n];
                int h = n >> 6, d = n & 63;
                int row = h * TS + (mb + i);
                dst[row * THD + d] = val;
                if (z == 0) Qc[(size_t)row * KC + d] = f2bf(val * 0.1125f);
                else Kc[(size_t)row * KC + d] = f2bf(val);
            }
    }
}

// ---------------- output projection: out = ctx @ Wo^T + bo ----------------
__global__ __launch_bounds__(256) void k_proj_out(
    const float* __restrict__ X, const float* __restrict__ W,
    const float* __restrict__ bias, float* __restrict__ out) {
    __shared__ float As[32][68];
    __shared__ float Bs[32][68];
    const int n0 = blockIdx.x * 64;
    const int m0 = blockIdx.y * 64;
    const int tid = threadIdx.x;
    float acc[4][4] = {};
    for (int k0 = 0; k0 < TH; k0 += 32) {
#pragma unroll
        for (int l = 0; l < 2; ++l) {
            int i = tid + l * 256;
            int row = i >> 3, col = (i & 7) << 2;
            float4 a = *(const float4*)&X[(m0 + row) * TH + k0 + col];
            As[col + 0][row] = a.x; As[col + 1][row] = a.y;
            As[col + 2][row] = a.z; As[col + 3][row] = a.w;
            float4 b = *(const float4*)&W[(n0 + row) * TH + k0 + col];
            Bs[col + 0][row] = b.x; Bs[col + 1][row] = b.y;
            Bs[col + 2][row] = b.z; Bs[col + 3][row] = b.w;
        }
        __syncthreads();
        fma16(acc, &As[0][0] + ((tid >> 4) << 2), &Bs[0][0] + ((tid & 15) << 2));
        __syncthreads();
    }
    const int mb = m0 + ((tid >> 4) << 2);
    const int nb = n0 + ((tid & 15) << 2);
#pragma unroll
    for (int i = 0; i < 4; ++i)
#pragma unroll
        for (int j = 0; j < 4; ++j) {
            int n = nb + j;
            out[(mb + i) * TH + n] = acc[i][j] + bias[n];
        }
}

// ---------------- row inverse norms for q,k ----------------
__global__ __launch_bounds__(64) void k_rownorm(
    const float* __restrict__ q, const float* __restrict__ kbuf,
    float* __restrict__ invq, float* __restrict__ invk) {
    const int row = blockIdx.x;
    const float* src = blockIdx.y ? kbuf : q;
    float* dst = blockIdx.y ? invk : invq;
    float x = src[row * THD + threadIdx.x];
    float ss = waveReduceSum(x * x);
    if (threadIdx.x == 0) dst[row] = 1.0f / (sqrtf(ss) + 1e-5f);
}

// ---------------- phi GEMM: Z = (x*inv) @ omega[h]^T ; write bf16(0.125*cos(Z+b)) ----------------
__global__ __launch_bounds__(256) void k_phi(
    const float* __restrict__ q, const float* __restrict__ kbuf,
    const float* __restrict__ invq, const float* __restrict__ invk,
    const float* __restrict__ omega, const float* __restrict__ rffb,
    short* __restrict__ Qc, short* __restrict__ Kc) {
    __shared__ float As[32][68];
    __shared__ float Bs[32][68];
    const int z = blockIdx.z;
    const int h = z >> 1, which = z & 1;
    const float* X = which ? kbuf : q;
    const float* inv = which ? invk : invq;
    short* dst = which ? Kc : Qc;
    const int n0 = blockIdx.x * 64;
    const int m0 = blockIdx.y * 64;
    const int tid = threadIdx.x;
    float acc[4][4] = {};
    for (int k0 = 0; k0 < THD; k0 += 32) {
#pragma unroll
        for (int l = 0; l < 2; ++l) {
            int i = tid + l * 256;
            int row = i >> 3, col = (i & 7) << 2;
            int rq = h * TS + m0 + row;
            float s = inv[rq];
            float4 a = *(const float4*)&X[rq * THD + k0 + col];
            As[col + 0][row] = a.x * s; As[col + 1][row] = a.y * s;
            As[col + 2][row] = a.z * s; As[col + 3][row] = a.w * s;
            float4 b = *(const float4*)&omega[(h * TNF + n0 + row) * THD + k0 + col];
            Bs[col + 0][row] = b.x; Bs[col + 1][row] = b.y;
            Bs[col + 2][row] = b.z; Bs[col + 3][row] = b.w;
        }
        __syncthreads();
        fma16(acc, &As[0][0] + ((tid >> 4) << 2), &Bs[0][0] + ((tid & 15) << 2));
        __syncthreads();
    }
    const int mb = m0 + ((tid >> 4) << 2);
    const int nb = n0 + ((tid & 15) << 2);
#pragma unroll
    for (int i = 0; i < 4; ++i)
#pragma unroll
        for (int j = 0; j < 4; ++j) {
            int f = nb + j;
            float zv = acc[i][j] + rffb[h * TNF + f];   // SIGMA = 1
            dst[(size_t)(h * TS + (mb + i)) * KC + 64 + f] = f2bf(0.125f * cosf(zv));
        }
}

// ---------------- phi row L2-normalize in place (bf16); fold (1-alpha)=0.1 into phi_q ----------------
__global__ __launch_bounds__(128) void k_phinorm(short* __restrict__ Qc, short* __restrict__ Kc) {
    const int row = blockIdx.x;
    short* buf = (blockIdx.y ? Kc : Qc) + (size_t)row * KC + 64;
    const float scale0 = blockIdx.y ? 1.0f : 0.1f;
    const int tid = threadIdx.x;
    float p = bf2f(buf[tid]);
    float ss = waveReduceSum(p * p);
    __shared__ float sh[2];
    if ((tid & 63) == 0) sh[tid >> 6] = ss;
    __syncthreads();
    ss = sh[0] + sh[1];
    float sc = scale0 / (sqrtf(ss) + 1e-6f);
    buf[tid] = f2bf(p * sc);
}

// ---------------- scores: bf16 MFMA concat-K GEMM (K = 192), 128x128 tile, 4 waves ----------------
__global__ __launch_bounds__(256) void k_scores_mfma(
    const short* __restrict__ Qc, const short* __restrict__ Kc,
    const float* __restrict__ mask, float* __restrict__ wout) {
    __shared__ __align__(16) short Asb[128][40];   // 80 B row stride: 16B-aligned, <=2-way bank alias
    __shared__ __align__(16) short Bsb[128][40];
    const int h = blockIdx.z;
    const int n0 = blockIdx.x * 128;
    const int m0 = blockIdx.y * 128;
    const int tid = threadIdx.x;
    const int lane = tid & 63;
    const int w = tid >> 6;
    const int wm = (w >> 1) * 64, wn = (w & 1) * 64;
    const int fr = lane & 15;          // fragment row/col within 16
    const int quad = lane >> 4;        // k-quad

    floatx4 acc[4][4] = {};

    for (int k0 = 0; k0 < KC; k0 += 32) {
#pragma unroll
        for (int l = 0; l < 2; ++l) {
            int c = tid + l * 256;
            int row = c >> 2, col = (c & 3) << 3;
            short8 a = *(const short8*)&Qc[(size_t)(h * TS + m0 + row) * KC + k0 + col];
            *(short8*)&Asb[row][col] = a;
            short8 b = *(const short8*)&Kc[(size_t)(h * TS + n0 + row) * KC + k0 + col];
            *(short8*)&Bsb[row][col] = b;
        }
        __syncthreads();
        bf16x8 af[4], bfr[4];
#pragma unroll
        for (int i = 0; i < 4; ++i) af[i] = *(const bf16x8*)&Asb[wm + i * 16 + fr][quad * 8];
#pragma unroll
        for (int j = 0; j < 4; ++j) bfr[j] = *(const bf16x8*)&Bsb[wn + j * 16 + fr][quad * 8];
#pragma unroll
        for (int i = 0; i < 4; ++i)
#pragma unroll
            for (int j = 0; j < 4; ++j)
                acc[i][j] = __builtin_amdgcn_mfma_f32_16x16x32_bf16(af[i], bfr[j], acc[i][j], 0, 0, 0);
        __syncthreads();
    }
    // epilogue: C/D layout col=lane&15, row=(lane>>4)*4+reg
#pragma unroll
    for (int j = 0; j < 4; ++j) {
        int col_g = n0 + wn + j * 16 + fr;
        float mb = (mask[col_g] - 1.0f) * 10000.0f;
#pragma unroll
        for (int i = 0; i < 4; ++i) {
#pragma unroll
            for (int r = 0; r < 4; ++r) {
                int row_g = m0 + wm + i * 16 + quad * 4 + r;
                wout[(size_t)(h * TS + row_g) * TS + col_g] = acc[i][j][r] + mb;
            }
        }
    }
}

// ---------------- softmax over rows of 2048, in place ----------------
__global__ __launch_bounds__(256) void k_softmax(float* __restrict__ wout) {
    const int row = blockIdx.x;
    float4* p = (float4*)(wout + (size_t)row * TS);
    const int tid = threadIdx.x;
    float4 x0 = p[tid], x1 = p[tid + 256];
    float mx = fmaxf(fmaxf(fmaxf(x0.x, x0.y), fmaxf(x0.z, x0.w)),
                     fmaxf(fmaxf(x1.x, x1.y), fmaxf(x1.z, x1.w)));
    mx = waveReduceMax(mx);
    __shared__ float rm[4];
    __shared__ float rs[4];
    if ((tid & 63) == 0) rm[tid >> 6] = mx;
    __syncthreads();
    mx = fmaxf(fmaxf(rm[0], rm[1]), fmaxf(rm[2], rm[3]));
    float e[8];
    e[0] = __expf(x0.x - mx); e[1] = __expf(x0.y - mx);
    e[2] = __expf(x0.z - mx); e[3] = __expf(x0.w - mx);
    e[4] = __expf(x1.x - mx); e[5] = __expf(x1.y - mx);
    e[6] = __expf(x1.z - mx); e[7] = __expf(x1.w - mx);
    float sum = ((e[0] + e[1]) + (e[2] + e[3])) + ((e[4] + e[5]) + (e[6] + e[7]));
    sum = waveReduceSum(sum);
    if ((tid & 63) == 0) rs[tid >> 6] = sum;
    __syncthreads();
    sum = rs[0] + rs[1] + rs[2] + rs[3];
    float rinv = 1.0f / sum;
    x0.x = e[0] * rinv; x0.y = e[1] * rinv; x0.z = e[2] * rinv; x0.w = e[3] * rinv;
    x1.x = e[4] * rinv; x1.y = e[5] * rinv; x1.z = e[6] * rinv; x1.w = e[7] * rinv;
    p[tid] = x0;
    p[tid + 256] = x1;
}

// ---------------- context GEMM (bf16 MFMA): ctx[s, h*64+d] = sum_t w[h,s,t] * v[h,t,d] ----------------
// A = wout (fp32, converted to bf16 during LDS staging), B = Vb (bf16, [h][d][t] N-major).
// 128x64 tile per block, 4 waves x (32 rows x 64 cols), K-step 32. Same fragment/LDS
// structure as k_scores_mfma (proven layout: [rows][40] short stride = 80B, <=2-way alias).
__global__ __launch_bounds__(256) void k_ctx_mfma(
    const float* __restrict__ wout, const short* __restrict__ Vb, float* __restrict__ ctx) {
    __shared__ __align__(16) short Asb[128][40];
    __shared__ __align__(16) short Bsb[64][40];
    const int h = blockIdx.y;
    const int m0 = blockIdx.x * 128;
    const int tid = threadIdx.x;
    const int lane = tid & 63;
    const int w = tid >> 6;
    const int wm = w * 32;             // wave's 32-row strip
    const int fr = lane & 15;
    const int quad = lane >> 4;
    floatx4 acc[2][4] = {};
    for (int k0 = 0; k0 < TS; k0 += 32) {
        // stage A: 128 rows x 32 k fp32 -> bf16 (4 float4 = 16 converts per thread)
#pragma unroll
        for (int l = 0; l < 4; ++l) {
            int idx = tid + l * 256;
            int row = idx >> 3, col = (idx & 7) << 2;
            float4 a = *(const float4*)&wout[(size_t)(h * TS + m0 + row) * TS + k0 + col];
            s16x4 s;
            s[0] = f2bf(a.x); s[1] = f2bf(a.y); s[2] = f2bf(a.z); s[3] = f2bf(a.w);
            *(s16x4*)&Asb[row][col] = s;
        }
        // stage B: 64 d-rows x 32 t (already bf16, N-major) — one short8 per thread
        {
            int row = tid >> 2, col = (tid & 3) << 3;
            *(short8*)&Bsb[row][col] =
                *(const short8*)&Vb[(size_t)(h * THD + row) * TS + k0 + col];
        }
        __syncthreads();
        bf16x8 af[2], bfr[4];
#pragma unroll
        for (int i = 0; i < 2; ++i) af[i] = *(const bf16x8*)&Asb[wm + i * 16 + fr][quad * 8];
#pragma unroll
        for (int j = 0; j < 4; ++j) bfr[j] = *(const bf16x8*)&Bsb[j * 16 + fr][quad * 8];
#pragma unroll
        for (int i = 0; i < 2; ++i)
#pragma unroll
            for (int j = 0; j < 4; ++j)
                acc[i][j] = __builtin_amdgcn_mfma_f32_16x16x32_bf16(af[i], bfr[j], acc[i][j], 0, 0, 0);
        __syncthreads();
    }
    // epilogue: C/D layout col=lane&15, row=(lane>>4)*4+reg
#pragma unroll
    for (int i = 0; i < 2; ++i)
#pragma unroll
        for (int j = 0; j < 4; ++j)
#pragma unroll
            for (int r = 0; r < 4; ++r) {
                int row_g = m0 + wm + i * 16 + quad * 4 + r;
                ctx[(size_t)row_g * TH + h * THD + j * 16 + fr] = acc[i][j][r];
            }
}

extern "C" void kernel_launch(void* const* d_in, const int* in_sizes, int n_in,
                              void* d_out, int out_size, void* d_ws, size_t ws_size,
                              hipStream_t stream) {
    const float* hs    = (const float*)d_in[0];
    const float* mask  = (const float*)d_in[1];
    const float* Wq    = (const float*)d_in[2];
    const float* bq    = (const float*)d_in[3];
    const float* Wk    = (const float*)d_in[4];
    const float* bk    = (const float*)d_in[5];
    const float* Wv    = (const float*)d_in[6];
    const float* bv    = (const float*)d_in[7];
    const float* Wo    = (const float*)d_in[8];
    const float* bo    = (const float*)d_in[9];
    const float* omega = (const float*)d_in[10];
    const float* rffb  = (const float*)d_in[11];

    float* out0 = (float*)d_out;               // (S,H) final output
    float* wout = out0 + TS * TH;              // (NH,S,S) attention weights

    // workspace layout (floats); total ~11.06M floats = ~44.2 MB
    float* ws   = (float*)d_ws;
    float* q    = ws;                          // NH*S*HD = 1572864
    float* kbuf = ws + 1572864;
    short* Vb   = (short*)(ws + 3145728);      // NH*HD*TS bf16 transposed V (fits old fp32 v slot)
    float* invq = ws + 4718592;                // NH*S = 24576
    float* invk = ws + 4743168;
    float* ctx  = ws + 4767744;                // S*H = 1572864
    short* Qc   = (short*)(ws + 6340608);      // NH*S*KC bf16 = 4718592 shorts
    short* Kc   = (short*)(ws + 8699904);

    k_proj_qkv<<<dim3(12, 32, 3), 256, 0, stream>>>(hs, Wq, bq, Wk, bk, Wv, bv, q, kbuf, Vb, Qc, Kc);
    k_rownorm<<<dim3(TNH * TS, 2), 64, 0, stream>>>(q, kbuf, invq, invk);
    k_phi<<<dim3(2, 32, 24), 256, 0, stream>>>(q, kbuf, invq, invk, omega, rffb, Qc, Kc);
    k_phinorm<<<dim3(TNH * TS, 2), 128, 0, stream>>>(Qc, Kc);
    k_scores_mfma<<<dim3(16, 16, 12), 256, 0, stream>>>(Qc, Kc, mask, wout);
    k_softmax<<<TNH * TS, 256, 0, stream>>>(wout);
    k_ctx_mfma<<<dim3(16, 12), 256, 0, stream>>>(wout, Vb, ctx);
    k_proj_out<<<dim3(12, 32), 256, 0, stream>>>(ctx, Wo, bo, out0);
}

// Round 3
// 503.985 us; speedup vs baseline: 1.2991x; 1.1875x over previous
//
#include <hip/hip_runtime.h>
#include <cmath>

#define TS 2048   // sequence
#define TH 768    // hidden
#define TNH 12    // heads
#define THD 64    // head dim
#define TNF 128   // rff features
#define KC 192    // concat K for scores (64 dot + 128 rff)

typedef __attribute__((ext_vector_type(4))) short s16x4;     // NOTE: 'short4' collides with HIP's vector types
typedef __attribute__((ext_vector_type(8))) short short8;
typedef __attribute__((ext_vector_type(8))) __bf16 bf16x8;   // matches builtin signature V8y
typedef __attribute__((ext_vector_type(4))) float floatx4;

// ---------------- fp32 <-> bf16 helpers ----------------
__device__ __forceinline__ short f2bf(float x) {
    union { float f; unsigned u; } v; v.f = x;
    unsigned r = v.u + 0x7FFFu + ((v.u >> 16) & 1u);   // round-nearest-even
    return (short)(r >> 16);
}
__device__ __forceinline__ float bf2f(short x) {
    union { unsigned u; float f; } v;
    v.u = ((unsigned)(unsigned short)x) << 16;
    return v.f;
}

// ---------------- wave helpers (wave = 64) ----------------
__device__ __forceinline__ float waveReduceSum(float v) {
#pragma unroll
    for (int off = 32; off >= 1; off >>= 1) v += __shfl_xor(v, off, 64);
    return v;
}
__device__ __forceinline__ float waveReduceMax(float v) {
#pragma unroll
    for (int off = 32; off >= 1; off >>= 1) v = fmaxf(v, __shfl_xor(v, off, 64));
    return v;
}

// ---------------- fp32 inner-product microkernel (kept for small GEMMs) ----------------
__device__ __forceinline__ void fma16(float (&acc)[4][4], const float* pa, const float* pb) {
#pragma unroll
    for (int kk = 0; kk < 32; ++kk) {
        float4 a = *(const float4*)(pa + kk * 68);
        float4 b = *(const float4*)(pb + kk * 68);
        float av[4] = {a.x, a.y, a.z, a.w};
        float bv[4] = {b.x, b.y, b.z, b.w};
#pragma unroll
        for (int i = 0; i < 4; ++i)
#pragma unroll
            for (int j = 0; j < 4; ++j) acc[i][j] += av[i] * bv[j];
    }
}

// ---------------- cvt: fp32 -> bf16 for hs and the three projection weights ----------------
__global__ __launch_bounds__(256) void k_cvt_bf16(
    const float* __restrict__ s0, const float* __restrict__ s1,
    const float* __restrict__ s2, const float* __restrict__ s3,
    short* __restrict__ d0, short* __restrict__ d1,
    short* __restrict__ d2, short* __restrict__ d3) {
    const int y = blockIdx.y;
    const float* src = (y == 0) ? s0 : ((y == 1) ? s1 : ((y == 2) ? s2 : s3));
    short* dst = (y == 0) ? d0 : ((y == 1) ? d1 : ((y == 2) ? d2 : d3));
    const int n4 = (y == 0) ? (TS * TH / 4) : (TH * TH / 4);
    for (int i = blockIdx.x * 256 + threadIdx.x; i < n4; i += gridDim.x * 256) {
        float4 v = ((const float4*)src)[i];
        s16x4 o;
        o[0] = f2bf(v.x); o[1] = f2bf(v.y); o[2] = f2bf(v.z); o[3] = f2bf(v.w);
        *(s16x4*)&dst[i * 4] = o;
    }
}

// ---------------- QKV projection (bf16 MFMA): Y = X @ W^T + b, scatter to (h,s,d) ----------------
// Same 128x128 tile / 4-wave / [128][40]-LDS structure as k_scores_mfma (proven).
// z==0 (q): dq fp32 + Qc[row][0:64] = bf16(0.1125 * q)   (alpha/sqrt(HD) folded)
// z==1 (k): dk fp32 + Kc[row][0:64] = bf16(k)
// z==2 (v): Vb[h][d][t] = bf16(v)  (transposed for the PV MFMA B-operand)
__global__ __launch_bounds__(256) void k_proj_qkv_mfma(
    const short* __restrict__ Xb,
    const short* __restrict__ Wqb, const short* __restrict__ Wkb, const short* __restrict__ Wvb,
    const float* __restrict__ b0, const float* __restrict__ b1, const float* __restrict__ b2,
    float* __restrict__ dq, float* __restrict__ dk, short* __restrict__ Vb,
    short* __restrict__ Qc, short* __restrict__ Kc) {
    __shared__ __align__(16) short Asb[128][40];
    __shared__ __align__(16) short Bsb[128][40];
    const int z = blockIdx.z;
    const short* W = (z == 0) ? Wqb : ((z == 1) ? Wkb : Wvb);
    const float* bias = (z == 0) ? b0 : ((z == 1) ? b1 : b2);
    const int n0 = blockIdx.x * 128;
    const int m0 = blockIdx.y * 128;
    const int tid = threadIdx.x;
    const int lane = tid & 63;
    const int w = tid >> 6;
    const int wm = (w >> 1) * 64, wn = (w & 1) * 64;
    const int fr = lane & 15;
    const int quad = lane >> 4;

    floatx4 acc[4][4] = {};

    for (int k0 = 0; k0 < TH; k0 += 32) {
#pragma unroll
        for (int l = 0; l < 2; ++l) {
            int c = tid + l * 256;
            int row = c >> 2, col = (c & 3) << 3;
            *(short8*)&Asb[row][col] = *(const short8*)&Xb[(size_t)(m0 + row) * TH + k0 + col];
            *(short8*)&Bsb[row][col] = *(const short8*)&W[(size_t)(n0 + row) * TH + k0 + col];
        }
        __syncthreads();
        bf16x8 af[4], bfr[4];
#pragma unroll
        for (int i = 0; i < 4; ++i) af[i] = *(const bf16x8*)&Asb[wm + i * 16 + fr][quad * 8];
#pragma unroll
        for (int j = 0; j < 4; ++j) bfr[j] = *(const bf16x8*)&Bsb[wn + j * 16 + fr][quad * 8];
#pragma unroll
        for (int i = 0; i < 4; ++i)
#pragma unroll
            for (int j = 0; j < 4; ++j)
                acc[i][j] = __builtin_amdgcn_mfma_f32_16x16x32_bf16(af[i], bfr[j], acc[i][j], 0, 0, 0);
        __syncthreads();
    }
    // epilogue: C/D layout col=lane&15, row=(lane>>4)*4+reg
    if (z == 2) {
#pragma unroll
        for (int j = 0; j < 4; ++j) {
            int n = n0 + wn + j * 16 + fr;
            int h = n >> 6, d = n & 63;
            float bv = bias[n];
#pragma unroll
            for (int i = 0; i < 4; ++i) {
                int t = m0 + wm + i * 16 + quad * 4;
                s16x4 pk;
#pragma unroll
                for (int r = 0; r < 4; ++r) pk[r] = f2bf(acc[i][j][r] + bv);
                *(s16x4*)&Vb[(size_t)(h * THD + d) * TS + t] = pk;
            }
        }
    } else {
        float* dst = z ? dk : dq;
        short* cc = z ? Kc : Qc;
        const float qs = z ? 1.0f : 0.1125f;
#pragma unroll
        for (int j = 0; j < 4; ++j) {
            int n = n0 + wn + j * 16 + fr;
            int h = n >> 6, d = n & 63;
            float bv = bias[n];
#pragma unroll
            for (int i = 0; i < 4; ++i) {
#pragma unroll
                for (int r = 0; r < 4; ++r) {
                    int m = m0 + wm + i * 16 + quad * 4 + r;
                    float val = acc[i][j][r] + bv;
                    size_t rowi = (size_t)(h * TS + m);
                    dst[rowi * THD + d] = val;
                    cc[rowi * KC + d] = f2bf(val * qs);
                }
            }
        }
    }
}

// ---------------- output projection: out = ctx @ Wo^T + bo ----------------
__global__ __launch_bounds__(256) void k_proj_out(
    const float* __restrict__ X, const float* __restrict__ W,
    const float* __restrict__ bias, float* __restrict__ out) {
    __shared__ float As[32][68];
    __shared__ float Bs[32][68];
    const int n0 = blockIdx.x * 64;
    const int m0 = blockIdx.y * 64;
    const int tid = threadIdx.x;
    float acc[4][4] = {};
    for (int k0 = 0; k0 < TH; k0 += 32) {
#pragma unroll
        for (int l = 0; l < 2; ++l) {
            int i = tid + l * 256;
            int row = i >> 3, col = (i & 7) << 2;
            float4 a = *(const float4*)&X[(m0 + row) * TH + k0 + col];
            As[col + 0][row] = a.x; As[col + 1][row] = a.y;
            As[col + 2][row] = a.z; As[col + 3][row] = a.w;
            float4 b = *(const float4*)&W[(n0 + row) * TH + k0 + col];
            Bs[col + 0][row] = b.x; Bs[col + 1][row] = b.y;
            Bs[col + 2][row] = b.z; Bs[col + 3][row] = b.w;
        }
        __syncthreads();
        fma16(acc, &As[0][0] + ((tid >> 4) << 2), &Bs[0][0] + ((tid & 15) << 2));
        __syncthreads();
    }
    const int mb = m0 + ((tid >> 4) << 2);
    const int nb = n0 + ((tid & 15) << 2);
#pragma unroll
    for (int i = 0; i < 4; ++i)
#pragma unroll
        for (int j = 0; j < 4; ++j) {
            int n = nb + j;
            out[(mb + i) * TH + n] = acc[i][j] + bias[n];
        }
}

// ---------------- row inverse norms for q,k ----------------
__global__ __launch_bounds__(64) void k_rownorm(
    const float* __restrict__ q, const float* __restrict__ kbuf,
    float* __restrict__ invq, float* __restrict__ invk) {
    const int row = blockIdx.x;
    const float* src = blockIdx.y ? kbuf : q;
    float* dst = blockIdx.y ? invk : invq;
    float x = src[row * THD + threadIdx.x];
    float ss = waveReduceSum(x * x);
    if (threadIdx.x == 0) dst[row] = 1.0f / (sqrtf(ss) + 1e-5f);
}

// ---------------- phi GEMM: Z = (x*inv) @ omega[h]^T ; write bf16(0.125*cos(Z+b)) ----------------
__global__ __launch_bounds__(256) void k_phi(
    const float* __restrict__ q, const float* __restrict__ kbuf,
    const float* __restrict__ invq, const float* __restrict__ invk,
    const float* __restrict__ omega, const float* __restrict__ rffb,
    short* __restrict__ Qc, short* __restrict__ Kc) {
    __shared__ float As[32][68];
    __shared__ float Bs[32][68];
    const int z = blockIdx.z;
    const int h = z >> 1, which = z & 1;
    const float* X = which ? kbuf : q;
    const float* inv = which ? invk : invq;
    short* dst = which ? Kc : Qc;
    const int n0 = blockIdx.x * 64;
    const int m0 = blockIdx.y * 64;
    const int tid = threadIdx.x;
    float acc[4][4] = {};
    for (int k0 = 0; k0 < THD; k0 += 32) {
#pragma unroll
        for (int l = 0; l < 2; ++l) {
            int i = tid + l * 256;
            int row = i >> 3, col = (i & 7) << 2;
            int rq = h * TS + m0 + row;
            float s = inv[rq];
            float4 a = *(const float4*)&X[rq * THD + k0 + col];
            As[col + 0][row] = a.x * s; As[col + 1][row] = a.y * s;
            As[col + 2][row] = a.z * s; As[col + 3][row] = a.w * s;
            float4 b = *(const float4*)&omega[(h * TNF + n0 + row) * THD + k0 + col];
            Bs[col + 0][row] = b.x; Bs[col + 1][row] = b.y;
            Bs[col + 2][row] = b.z; Bs[col + 3][row] = b.w;
        }
        __syncthreads();
        fma16(acc, &As[0][0] + ((tid >> 4) << 2), &Bs[0][0] + ((tid & 15) << 2));
        __syncthreads();
    }
    const int mb = m0 + ((tid >> 4) << 2);
    const int nb = n0 + ((tid & 15) << 2);
#pragma unroll
    for (int i = 0; i < 4; ++i)
#pragma unroll
        for (int j = 0; j < 4; ++j) {
            int f = nb + j;
            float zv = acc[i][j] + rffb[h * TNF + f];   // SIGMA = 1
            dst[(size_t)(h * TS + (mb + i)) * KC + 64 + f] = f2bf(0.125f * cosf(zv));
        }
}

// ---------------- phi row L2-normalize in place (bf16); fold (1-alpha)=0.1 into phi_q ----------------
__global__ __launch_bounds__(128) void k_phinorm(short* __restrict__ Qc, short* __restrict__ Kc) {
    const int row = blockIdx.x;
    short* buf = (blockIdx.y ? Kc : Qc) + (size_t)row * KC + 64;
    const float scale0 = blockIdx.y ? 1.0f : 0.1f;
    const int tid = threadIdx.x;
    float p = bf2f(buf[tid]);
    float ss = waveReduceSum(p * p);
    __shared__ float sh[2];
    if ((tid & 63) == 0) sh[tid >> 6] = ss;
    __syncthreads();
    ss = sh[0] + sh[1];
    float sc = scale0 / (sqrtf(ss) + 1e-6f);
    buf[tid] = f2bf(p * sc);
}

// ---------------- scores: bf16 MFMA concat-K GEMM (K = 192), 128x128 tile, 4 waves ----------------
__global__ __launch_bounds__(256) void k_scores_mfma(
    const short* __restrict__ Qc, const short* __restrict__ Kc,
    const float* __restrict__ mask, float* __restrict__ wout) {
    __shared__ __align__(16) short Asb[128][40];   // 80 B row stride: 16B-aligned, <=2-way bank alias
    __shared__ __align__(16) short Bsb[128][40];
    const int h = blockIdx.z;
    const int n0 = blockIdx.x * 128;
    const int m0 = blockIdx.y * 128;
    const int tid = threadIdx.x;
    const int lane = tid & 63;
    const int w = tid >> 6;
    const int wm = (w >> 1) * 64, wn = (w & 1) * 64;
    const int fr = lane & 15;          // fragment row/col within 16
    const int quad = lane >> 4;        // k-quad

    floatx4 acc[4][4] = {};

    for (int k0 = 0; k0 < KC; k0 += 32) {
#pragma unroll
        for (int l = 0; l < 2; ++l) {
            int c = tid + l * 256;
            int row = c >> 2, col = (c & 3) << 3;
            short8 a = *(const short8*)&Qc[(size_t)(h * TS + m0 + row) * KC + k0 + col];
            *(short8*)&Asb[row][col] = a;
            short8 b = *(const short8*)&Kc[(size_t)(h * TS + n0 + row) * KC + k0 + col];
            *(short8*)&Bsb[row][col] = b;
        }
        __syncthreads();
        bf16x8 af[4], bfr[4];
#pragma unroll
        for (int i = 0; i < 4; ++i) af[i] = *(const bf16x8*)&Asb[wm + i * 16 + fr][quad * 8];
#pragma unroll
        for (int j = 0; j < 4; ++j) bfr[j] = *(const bf16x8*)&Bsb[wn + j * 16 + fr][quad * 8];
#pragma unroll
        for (int i = 0; i < 4; ++i)
#pragma unroll
            for (int j = 0; j < 4; ++j)
                acc[i][j] = __builtin_amdgcn_mfma_f32_16x16x32_bf16(af[i], bfr[j], acc[i][j], 0, 0, 0);
        __syncthreads();
    }
    // epilogue: C/D layout col=lane&15, row=(lane>>4)*4+reg
#pragma unroll
    for (int j = 0; j < 4; ++j) {
        int col_g = n0 + wn + j * 16 + fr;
        float mb = (mask[col_g] - 1.0f) * 10000.0f;
#pragma unroll
        for (int i = 0; i < 4; ++i) {
#pragma unroll
            for (int r = 0; r < 4; ++r) {
                int row_g = m0 + wm + i * 16 + quad * 4 + r;
                wout[(size_t)(h * TS + row_g) * TS + col_g] = acc[i][j][r] + mb;
            }
        }
    }
}

// ---------------- softmax over rows of 2048, in place ----------------
__global__ __launch_bounds__(256) void k_softmax(float* __restrict__ wout) {
    const int row = blockIdx.x;
    float4* p = (float4*)(wout + (size_t)row * TS);
    const int tid = threadIdx.x;
    float4 x0 = p[tid], x1 = p[tid + 256];
    float mx = fmaxf(fmaxf(fmaxf(x0.x, x0.y), fmaxf(x0.z, x0.w)),
                     fmaxf(fmaxf(x1.x, x1.y), fmaxf(x1.z, x1.w)));
    mx = waveReduceMax(mx);
    __shared__ float rm[4];
    __shared__ float rs[4];
    if ((tid & 63) == 0) rm[tid >> 6] = mx;
    __syncthreads();
    mx = fmaxf(fmaxf(rm[0], rm[1]), fmaxf(rm[2], rm[3]));
    float e[8];
    e[0] = __expf(x0.x - mx); e[1] = __expf(x0.y - mx);
    e[2] = __expf(x0.z - mx); e[3] = __expf(x0.w - mx);
    e[4] = __expf(x1.x - mx); e[5] = __expf(x1.y - mx);
    e[6] = __expf(x1.z - mx); e[7] = __expf(x1.w - mx);
    float sum = ((e[0] + e[1]) + (e[2] + e[3])) + ((e[4] + e[5]) + (e[6] + e[7]));
    sum = waveReduceSum(sum);
    if ((tid & 63) == 0) rs[tid >> 6] = sum;
    __syncthreads();
    sum = rs[0] + rs[1] + rs[2] + rs[3];
    float rinv = 1.0f / sum;
    x0.x = e[0] * rinv; x0.y = e[1] * rinv; x0.z = e[2] * rinv; x0.w = e[3] * rinv;
    x1.x = e[4] * rinv; x1.y = e[5] * rinv; x1.z = e[6] * rinv; x1.w = e[7] * rinv;
    p[tid] = x0;
    p[tid + 256] = x1;
}

// ---------------- context GEMM (bf16 MFMA): ctx[s, h*64+d] = sum_t w[h,s,t] * v[h,t,d] ----------------
__global__ __launch_bounds__(256) void k_ctx_mfma(
    const float* __restrict__ wout, const short* __restrict__ Vb, float* __restrict__ ctx) {
    __shared__ __align__(16) short Asb[128][40];
    __shared__ __align__(16) short Bsb[64][40];
    const int h = blockIdx.y;
    const int m0 = blockIdx.x * 128;
    const int tid = threadIdx.x;
    const int lane = tid & 63;
    const int w = tid >> 6;
    const int wm = w * 32;             // wave's 32-row strip
    const int fr = lane & 15;
    const int quad = lane >> 4;
    floatx4 acc[2][4] = {};
    for (int k0 = 0; k0 < TS; k0 += 32) {
        // stage A: 128 rows x 32 k fp32 -> bf16 (4 float4 = 16 converts per thread)
#pragma unroll
        for (int l = 0; l < 4; ++l) {
            int idx = tid + l * 256;
            int row = idx >> 3, col = (idx & 7) << 2;
            float4 a = *(const float4*)&wout[(size_t)(h * TS + m0 + row) * TS + k0 + col];
            s16x4 s;
            s[0] = f2bf(a.x); s[1] = f2bf(a.y); s[2] = f2bf(a.z); s[3] = f2bf(a.w);
            *(s16x4*)&Asb[row][col] = s;
        }
        // stage B: 64 d-rows x 32 t (already bf16, N-major) — one short8 per thread
        {
            int row = tid >> 2, col = (tid & 3) << 3;
            *(short8*)&Bsb[row][col] =
                *(const short8*)&Vb[(size_t)(h * THD + row) * TS + k0 + col];
        }
        __syncthreads();
        bf16x8 af[2], bfr[4];
#pragma unroll
        for (int i = 0; i < 2; ++i) af[i] = *(const bf16x8*)&Asb[wm + i * 16 + fr][quad * 8];
#pragma unroll
        for (int j = 0; j < 4; ++j) bfr[j] = *(const bf16x8*)&Bsb[j * 16 + fr][quad * 8];
#pragma unroll
        for (int i = 0; i < 2; ++i)
#pragma unroll
            for (int j = 0; j < 4; ++j)
                acc[i][j] = __builtin_amdgcn_mfma_f32_16x16x32_bf16(af[i], bfr[j], acc[i][j], 0, 0, 0);
        __syncthreads();
    }
    // epilogue: C/D layout col=lane&15, row=(lane>>4)*4+reg
#pragma unroll
    for (int i = 0; i < 2; ++i)
#pragma unroll
        for (int j = 0; j < 4; ++j)
#pragma unroll
            for (int r = 0; r < 4; ++r) {
                int row_g = m0 + wm + i * 16 + quad * 4 + r;
                ctx[(size_t)row_g * TH + h * THD + j * 16 + fr] = acc[i][j][r];
            }
}

extern "C" void kernel_launch(void* const* d_in, const int* in_sizes, int n_in,
                              void* d_out, int out_size, void* d_ws, size_t ws_size,
                              hipStream_t stream) {
    const float* hs    = (const float*)d_in[0];
    const float* mask  = (const float*)d_in[1];
    const float* Wq    = (const float*)d_in[2];
    const float* bq    = (const float*)d_in[3];
    const float* Wk    = (const float*)d_in[4];
    const float* bk    = (const float*)d_in[5];
    const float* Wv    = (const float*)d_in[6];
    const float* bv    = (const float*)d_in[7];
    const float* Wo    = (const float*)d_in[8];
    const float* bo    = (const float*)d_in[9];
    const float* omega = (const float*)d_in[10];
    const float* rffb  = (const float*)d_in[11];

    float* out0 = (float*)d_out;               // (S,H) final output
    float* wout = out0 + TS * TH;              // (NH,S,S) attention weights

    // workspace layout (floats); total ~11.06M floats = ~44.2 MB
    float* ws   = (float*)d_ws;
    float* q    = ws;                          // NH*S*HD = 1572864
    float* kbuf = ws + 1572864;
    short* Vb   = (short*)(ws + 3145728);      // NH*HD*TS bf16 transposed V (fits old fp32 v slot)
    float* invq = ws + 4718592;                // NH*S = 24576
    float* invk = ws + 4743168;
    float* ctx  = ws + 4767744;                // S*H = 1572864
    short* Qc   = (short*)(ws + 6340608);      // NH*S*KC bf16 = 4718592 shorts
    short* Kc   = (short*)(ws + 8699904);

    // bf16 staging for the QKV projection, overlaid on wout (written only later by k_scores_mfma)
    short* Xb  = (short*)wout;                 // TS*TH shorts
    short* Wqb = Xb + (size_t)TS * TH;         // TH*TH shorts each
    short* Wkb = Wqb + (size_t)TH * TH;
    short* Wvb = Wkb + (size_t)TH * TH;

    k_cvt_bf16<<<dim3(512, 4), 256, 0, stream>>>(hs, Wq, Wk, Wv, Xb, Wqb, Wkb, Wvb);
    k_proj_qkv_mfma<<<dim3(6, 16, 3), 256, 0, stream>>>(Xb, Wqb, Wkb, Wvb, bq, bk, bv,
                                                        q, kbuf, Vb, Qc, Kc);
    k_rownorm<<<dim3(TNH * TS, 2), 64, 0, stream>>>(q, kbuf, invq, invk);
    k_phi<<<dim3(2, 32, 24), 256, 0, stream>>>(q, kbuf, invq, invk, omega, rffb, Qc, Kc);
    k_phinorm<<<dim3(TNH * TS, 2), 128, 0, stream>>>(Qc, Kc);
    k_scores_mfma<<<dim3(16, 16, 12), 256, 0, stream>>>(Qc, Kc, mask, wout);
    k_softmax<<<TNH * TS, 256, 0, stream>>>(wout);
    k_ctx_mfma<<<dim3(16, 12), 256, 0, stream>>>(wout, Vb, ctx);
    k_proj_out<<<dim3(12, 32), 256, 0, stream>>>(ctx, Wo, bo, out0);
}